// Round 10
// baseline (4164.450 us; speedup 1.0000x reference)
//
#include <hip/hip_runtime.h>
#include <math.h>

// Problem dims (fixed by the reference)
#define BN    32          // batch
#define TN    512         // TFs
#define GN    2000        // genes
#define PPGN  10          // peaks per gene
#define PN    (GN*PPGN)   // 20000 peaks
#define EN    64000       // edges
#define NOUTN 10          // output channels
#define PQN   (PN/4)      // 5000 p-quads (float4 granules)

#define TCH   8           // number of t-chunks
#define TPC   (TN/TCH)    // 64 t per chunk
#define BQ    4           // batch quarters
#define BPH   (BN/BQ)     // 8 batches per thread

#define REP   6           // probe: sweeps of the full 1.31GB x buffer

typedef float float4v __attribute__((ext_vector_type(4)));

// ---------------- MEASUREMENT PROBES (this round only) ----------------
// Purpose: measure the chip's PURE-READ HBM ceiling on this exact buffer.
// Every prior roofline estimate assumed reads can hit 6.3 TB/s; only writes
// (6.4, harness fills) were ever verified. Each probe reads 6x1.31GB=7.86GB
// so its dispatch outranks the ~830us fills in the top-5 table.
// lin_plain vs lin_nt isolates cache policy; lin vs r8pat isolates pattern.

__global__ __launch_bounds__(256)
void k_probe_lin_plain(const float* __restrict__ x, float* __restrict__ po) {
    const float4v* xp = (const float4v*)x;
    const size_t n4 = (size_t)BN * TN * PQN;        // 81,920,000 quads
    const size_t stride = (size_t)2048 * 256;
    size_t i0 = (size_t)blockIdx.x * 256 + threadIdx.x;
    float4v acc = {0.f, 0.f, 0.f, 0.f};
    for (int r = 0; r < REP; ++r) {
#pragma unroll 4
        for (size_t i = i0; i < n4; i += stride)
            acc += xp[i];
    }
    po[i0] = acc.x + acc.y + acc.z + acc.w;
}

__global__ __launch_bounds__(256)
void k_probe_lin_nt(const float* __restrict__ x, float* __restrict__ po) {
    const float4v* xp = (const float4v*)x;
    const size_t n4 = (size_t)BN * TN * PQN;
    const size_t stride = (size_t)2048 * 256;
    size_t i0 = (size_t)blockIdx.x * 256 + threadIdx.x;
    float4v acc = {0.f, 0.f, 0.f, 0.f};
    for (int r = 0; r < REP; ++r) {
#pragma unroll 4
        for (size_t i = i0; i < n4; i += stride)
            acc += __builtin_nontemporal_load(xp + i);
    }
    po[i0] = acc.x + acc.y + acc.z + acc.w;
}

// Exact R8 k_perpeak x-access pattern (8 b-streams/thread, 80KB t-hops),
// minus the W read and partial store.
__global__ __launch_bounds__(256)
void k_probe_r8_nt(const float* __restrict__ x, float* __restrict__ po) {
    int ptile = blockIdx.x;             // 0..19
    int bq    = blockIdx.y;             // 0..3
    int tc    = blockIdx.z;             // 0..7
    int pq    = ptile * 256 + threadIdx.x;
    if (pq >= PQN) return;
    int b0 = bq * BPH;
    int t0 = tc * TPC;
    const float4v* xp = (const float4v*)x + ((size_t)b0 * TN + t0) * PQN + pq;
    float4v acc = {0.f, 0.f, 0.f, 0.f};
    for (int r = 0; r < REP; ++r) {
#pragma unroll 2
        for (int t = 0; t < TPC; ++t) {
#pragma unroll
            for (int j = 0; j < BPH; ++j)
                acc += __builtin_nontemporal_load(xp + ((size_t)j * TN + t) * PQN);
        }
    }
    size_t gid = ((size_t)((blockIdx.z * 4 + blockIdx.y) * 20 + blockIdx.x)) * 256
               + threadIdx.x;
    po[gid] = acc.x + acc.y + acc.z + acc.w;
}

// ---------------- PIPELINE (bit-identical to R8) ----------------

__global__ __launch_bounds__(256)
void k_perpeak(const float* __restrict__ x,
               const float* __restrict__ W_sub,
               float* __restrict__ partial) {
    int ptile = blockIdx.x;             // 0..19 (fast axis)
    int bq    = blockIdx.y;             // 0..3
    int tc    = blockIdx.z;             // 0..7
    int pq    = ptile * 256 + threadIdx.x;
    if (pq >= PQN) return;              // last ptile: 136/256 active
    int b0 = bq * BPH;
    int t0 = tc * TPC;

    const float4v* xp = (const float4v*)x + ((size_t)b0 * TN + t0) * PQN + pq;
    const float4v* wp = (const float4v*)W_sub + (size_t)t0 * PQN + pq;

    float4v acc[BPH];
#pragma unroll
    for (int j = 0; j < BPH; ++j) acc[j] = (float4v){0.f, 0.f, 0.f, 0.f};

#pragma unroll 2
    for (int t = 0; t < TPC; ++t) {
        float4v wv = wp[(size_t)t * PQN];
#pragma unroll
        for (int j = 0; j < BPH; ++j) {
            float4v xv = __builtin_nontemporal_load(xp + ((size_t)j * TN + t) * PQN);
            acc[j] = xv * wv + acc[j];
        }
    }

    float4v* pp = (float4v*)partial + ((size_t)tc * BN + b0) * PQN + pq;
#pragma unroll
    for (int j = 0; j < BPH; ++j)
        __builtin_nontemporal_store(acc[j], pp + (size_t)j * PQN);
}

__global__ void k_h(const float* __restrict__ partial,
                    const float* __restrict__ b_sub,
                    float* __restrict__ h) {
    int idx = blockIdx.x * blockDim.x + threadIdx.x;
    if (idx >= BN * GN) return;
    int g = idx % GN, b = idx / GN;
    float s = b_sub[g];
    for (int tc = 0; tc < TCH; ++tc) {
        const float* pp = partial + ((size_t)tc * BN + b) * PN + g * PPGN;
#pragma unroll
        for (int k = 0; k < PPGN; ++k) s += pp[k];
    }
    h[idx] = fmaxf(s, 0.0f);
}

__global__ void k_deg(const int* __restrict__ col, float* __restrict__ deg) {
    int e = blockIdx.x * blockDim.x + threadIdx.x;
    if (e < EN) atomicAdd(&deg[col[e]], 1.0f);
}

__global__ void k_dinv(const float* __restrict__ deg, float* __restrict__ dinv) {
    int g = blockIdx.x * blockDim.x + threadIdx.x;
    if (g < GN) {
        float d = deg[g];
        dinv[g] = (d > 0.0f) ? (1.0f / sqrtf(d)) : 0.0f;
    }
}

__global__ __launch_bounds__(256)
void k_s(const int* __restrict__ row, const int* __restrict__ col,
         const float* __restrict__ dinv, const float* __restrict__ h,
         float* __restrict__ s) {
    __shared__ float s_lds[GN];
    int b = blockIdx.x;
    for (int g = threadIdx.x; g < GN; g += 256) s_lds[g] = 0.0f;
    __syncthreads();
    const float* hb = h + (size_t)b * GN;
    for (int e = threadIdx.x; e < EN; e += 256) {
        int r = row[e], c = col[e];
        float nrm = dinv[r] * dinv[c];
        atomicAdd(&s_lds[c], nrm * hb[r]);
    }
    __syncthreads();
    for (int g = threadIdx.x; g < GN; g += 256)
        s[(size_t)b * GN + g] = s_lds[g];
}

__global__ void k_out(const float* __restrict__ s,
                      const float* __restrict__ W_gcn,
                      const float* __restrict__ b_gcn,
                      const float* __restrict__ W_out,
                      const float* __restrict__ b_out,
                      float* __restrict__ out) {
    int b = blockIdx.x / NOUTN;
    int n = blockIdx.x % NOUTN;
    int lane = threadIdx.x;

    float w0 = W_gcn[0], w1 = W_gcn[1];
    float c0 = b_gcn[0], c1 = b_gcn[1];

    float acc = 0.0f;
    for (int g = lane; g < GN; g += 64) {
        float sv = s[(size_t)b * GN + g];
        float g0 = fmaxf(fmaf(sv, w0, c0), 0.0f);
        float g1 = fmaxf(fmaf(sv, w1, c1), 0.0f);
        const float* wo = &W_out[(size_t)n * (GN * 2) + 2 * g];
        acc = fmaf(g0, wo[0], acc);
        acc = fmaf(g1, wo[1], acc);
    }
#pragma unroll
    for (int off = 32; off > 0; off >>= 1)
        acc += __shfl_down(acc, off);
    if (lane == 0) out[b * NOUTN + n] = acc + b_out[n];
}

extern "C" void kernel_launch(void* const* d_in, const int* in_sizes, int n_in,
                              void* d_out, int out_size, void* d_ws, size_t ws_size,
                              hipStream_t stream) {
    const float* x         = (const float*)d_in[0];
    const int*   edge_index= (const int*)  d_in[1];
    const float* W_sub     = (const float*)d_in[2];
    const float* b_sub     = (const float*)d_in[3];
    const float* W_gcn     = (const float*)d_in[4];
    const float* b_gcn     = (const float*)d_in[5];
    const float* W_out     = (const float*)d_in[6];
    const float* b_out     = (const float*)d_in[7];
    float* out = (float*)d_out;

    char* ws = (char*)d_ws;
    // partial: TCH*BN*PN floats = 8*32*20000*4B = 20,480,000 B
    float* partial = (float*)(ws);
    float* h       = (float*)(ws + 20480000);       // B*G floats = 256,000 B
    float* deg     = (float*)(ws + 20736000);       // G   floats =   8,000 B
    float* dinv    = (float*)(ws + 20744000);       // G   floats =   8,000 B
    float* s       = (float*)(ws + 20752000);       // B*G floats = 256,000 B
    float* po1     = (float*)(ws + 32000000);       // 2,097,152 B
    float* po2     = (float*)(ws + 35000000);       // 2,097,152 B
    float* po3     = (float*)(ws + 38000000);       //   655,360 B

    const int* row = edge_index;        // edge_index[0,:]
    const int* col = edge_index + EN;   // edge_index[1,:]

    // ---- probes (measurement round) ----
    k_probe_lin_plain<<<2048, 256, 0, stream>>>(x, po1);
    k_probe_lin_nt   <<<2048, 256, 0, stream>>>(x, po2);
    dim3 grid_pp(20, BQ, TCH);
    k_probe_r8_nt    <<<grid_pp, 256, 0, stream>>>(x, po3);

    // ---- pipeline (identical to R8) ----
    hipMemsetAsync(deg, 0, GN * sizeof(float), stream);
    k_perpeak<<<grid_pp, 256, 0, stream>>>(x, W_sub, partial);
    k_h      <<<((BN * GN) + 255) / 256, 256, 0, stream>>>(partial, b_sub, h);
    k_deg    <<<(EN + 255) / 256,        256, 0, stream>>>(col, deg);
    k_dinv   <<<(GN + 255) / 256,        256, 0, stream>>>(deg, dinv);
    k_s      <<<BN, 256, 0, stream>>>(row, col, dinv, h, s);
    k_out    <<<BN * NOUTN, 64, 0, stream>>>(s, W_gcn, b_gcn, W_out, b_out, out);
}

// Round 11
// 360.742 us; speedup vs baseline: 11.5441x; 11.5441x over previous
//
#include <hip/hip_runtime.h>
#include <math.h>

// Problem dims (fixed by the reference)
#define BN    32          // batch
#define TN    512         // TFs
#define GN    2000        // genes
#define PPGN  10          // peaks per gene
#define PN    (GN*PPGN)   // 20000 peaks
#define EN    64000       // edges
#define NOUTN 10          // output channels
#define PQN   (PN/4)      // 5000 p-quads (float4 granules)

#define TCH   8           // number of t-chunks
#define TPC   (TN/TCH)    // 64 t per chunk
#define BQ    4           // batch quarters
#define BPH   (BN/BQ)     // 8 batches per thread
#define TW    8           // t-batch: W quads preloaded to registers

typedef float float4v __attribute__((ext_vector_type(4)));

// Stage 1 (R10 probes): R8's x-pattern ALONE sustains ~6.7 TB/s with nt loads
// (r8_nt probe ~1175us/7.86GB); cached linear is the slowest (5.4 TB/s demand,
// L2-polluting). k_perpeak's ~4.5 TB/s therefore comes from the 1:8
// interleave of cached W loads into the nt x stream: vmcnt completion is
// in-order, so one W L2-miss (~900cyc) blocks counting of the x loads queued
// behind it, and the per-iter FMA chain drains vmcnt every body. Fix: batch W
// 8-at-a-time into registers (one cached burst per 64 x loads), then stream
// 8x8 nt x-loads + FMAs -> x stream uninterrupted, W stall amortized 8x.
// Grid/traffic identical to R8 (20x4x8 blocks, ~1.47GB).
__global__ __launch_bounds__(256)
void k_perpeak(const float* __restrict__ x,
               const float* __restrict__ W_sub,
               float* __restrict__ partial) {
    int ptile = blockIdx.x;             // 0..19 (fast axis)
    int bq    = blockIdx.y;             // 0..3
    int tc    = blockIdx.z;             // 0..7
    int pq    = ptile * 256 + threadIdx.x;
    if (pq >= PQN) return;              // last ptile: 136/256 active
    int b0 = bq * BPH;
    int t0 = tc * TPC;

    const float4v* xp = (const float4v*)x + ((size_t)b0 * TN + t0) * PQN + pq;
    const float4v* wp = (const float4v*)W_sub + (size_t)t0 * PQN + pq;

    float4v acc[BPH];
#pragma unroll
    for (int j = 0; j < BPH; ++j) acc[j] = (float4v){0.f, 0.f, 0.f, 0.f};

#pragma unroll 1
    for (int t8 = 0; t8 < TPC; t8 += TW) {
        // batched cached W burst (8 loads, one in-order wait point)
        float4v wv[TW];
#pragma unroll
        for (int u = 0; u < TW; ++u)
            wv[u] = wp[(size_t)(t8 + u) * PQN];
        // uninterrupted nt x stream: 64 loads, FMAs from registers
#pragma unroll
        for (int j = 0; j < BPH; ++j) {
#pragma unroll
            for (int u = 0; u < TW; ++u) {
                float4v xv = __builtin_nontemporal_load(
                    xp + ((size_t)j * TN + t8 + u) * PQN);
                acc[j] = xv * wv[u] + acc[j];
            }
        }
    }

    float4v* pp = (float4v*)partial + ((size_t)tc * BN + b0) * PQN + pq;
#pragma unroll
    for (int j = 0; j < BPH; ++j)
        __builtin_nontemporal_store(acc[j], pp + (size_t)j * PQN);
}

// Stage 2: h[b,g] = relu(b_sub[g] + sum_tc sum_{k<10} partial[tc][b][g*10+k])
__global__ void k_h(const float* __restrict__ partial,
                    const float* __restrict__ b_sub,
                    float* __restrict__ h) {
    int idx = blockIdx.x * blockDim.x + threadIdx.x;
    if (idx >= BN * GN) return;
    int g = idx % GN, b = idx / GN;
    float s = b_sub[g];
    for (int tc = 0; tc < TCH; ++tc) {
        const float* pp = partial + ((size_t)tc * BN + b) * PN + g * PPGN;
#pragma unroll
        for (int k = 0; k < PPGN; ++k) s += pp[k];
    }
    h[idx] = fmaxf(s, 0.0f);
}

// Stage 3a: degree of target nodes (col)
__global__ void k_deg(const int* __restrict__ col, float* __restrict__ deg) {
    int e = blockIdx.x * blockDim.x + threadIdx.x;
    if (e < EN) atomicAdd(&deg[col[e]], 1.0f);
}

// Stage 3b: dinv = deg^-1/2 (0 where deg == 0)
__global__ void k_dinv(const float* __restrict__ deg, float* __restrict__ dinv) {
    int g = blockIdx.x * blockDim.x + threadIdx.x;
    if (g < GN) {
        float d = deg[g];
        dinv[g] = (d > 0.0f) ? (1.0f / sqrtf(d)) : 0.0f;
    }
}

// Stage 3c: s[b,g] = sum_{e: col[e]==g} dinv[row]*dinv[col] * h[b,row]
// One block per batch; accumulate in LDS (8KB) with LDS atomics, single
// non-atomic writeback.
__global__ __launch_bounds__(256)
void k_s(const int* __restrict__ row, const int* __restrict__ col,
         const float* __restrict__ dinv, const float* __restrict__ h,
         float* __restrict__ s) {
    __shared__ float s_lds[GN];
    int b = blockIdx.x;
    for (int g = threadIdx.x; g < GN; g += 256) s_lds[g] = 0.0f;
    __syncthreads();
    const float* hb = h + (size_t)b * GN;
    for (int e = threadIdx.x; e < EN; e += 256) {
        int r = row[e], c = col[e];
        float nrm = dinv[r] * dinv[c];
        atomicAdd(&s_lds[c], nrm * hb[r]);
    }
    __syncthreads();
    for (int g = threadIdx.x; g < GN; g += 256)
        s[(size_t)b * GN + g] = s_lds[g];
}

// Stage 4: out[b,n] = sum_g sum_c relu(W_gcn[c]*s[b,g]+b_gcn[c]) * W_out[n,2g+c] + b_out[n]
// One wave (64 threads) per (b,n).
__global__ void k_out(const float* __restrict__ s,
                      const float* __restrict__ W_gcn,
                      const float* __restrict__ b_gcn,
                      const float* __restrict__ W_out,
                      const float* __restrict__ b_out,
                      float* __restrict__ out) {
    int b = blockIdx.x / NOUTN;
    int n = blockIdx.x % NOUTN;
    int lane = threadIdx.x;

    float w0 = W_gcn[0], w1 = W_gcn[1];
    float c0 = b_gcn[0], c1 = b_gcn[1];

    float acc = 0.0f;
    for (int g = lane; g < GN; g += 64) {
        float sv = s[(size_t)b * GN + g];
        float g0 = fmaxf(fmaf(sv, w0, c0), 0.0f);
        float g1 = fmaxf(fmaf(sv, w1, c1), 0.0f);
        const float* wo = &W_out[(size_t)n * (GN * 2) + 2 * g];
        acc = fmaf(g0, wo[0], acc);
        acc = fmaf(g1, wo[1], acc);
    }
#pragma unroll
    for (int off = 32; off > 0; off >>= 1)
        acc += __shfl_down(acc, off);
    if (lane == 0) out[b * NOUTN + n] = acc + b_out[n];
}

extern "C" void kernel_launch(void* const* d_in, const int* in_sizes, int n_in,
                              void* d_out, int out_size, void* d_ws, size_t ws_size,
                              hipStream_t stream) {
    const float* x         = (const float*)d_in[0];
    const int*   edge_index= (const int*)  d_in[1];
    const float* W_sub     = (const float*)d_in[2];
    const float* b_sub     = (const float*)d_in[3];
    const float* W_gcn     = (const float*)d_in[4];
    const float* b_gcn     = (const float*)d_in[5];
    const float* W_out     = (const float*)d_in[6];
    const float* b_out     = (const float*)d_in[7];
    float* out = (float*)d_out;

    char* ws = (char*)d_ws;
    // partial: TCH*BN*PN floats = 8*32*20000*4B = 20,480,000 B
    float* partial = (float*)(ws);
    float* h       = (float*)(ws + 20480000);       // B*G floats = 256,000 B
    float* deg     = (float*)(ws + 20736000);       // G   floats =   8,000 B
    float* dinv    = (float*)(ws + 20744000);       // G   floats =   8,000 B
    float* s       = (float*)(ws + 20752000);       // B*G floats = 256,000 B

    const int* row = edge_index;        // edge_index[0,:]
    const int* col = edge_index + EN;   // edge_index[1,:]

    // deg is atomically accumulated -> zero it every call (graph-capture legal)
    hipMemsetAsync(deg, 0, GN * sizeof(float), stream);

    dim3 grid_pp(20, BQ, TCH);   // x = p-tile (fast), y = b-quarter, z = t-chunk
    k_perpeak<<<grid_pp, 256, 0, stream>>>(x, W_sub, partial);
    k_h      <<<((BN * GN) + 255) / 256, 256, 0, stream>>>(partial, b_sub, h);
    k_deg    <<<(EN + 255) / 256,        256, 0, stream>>>(col, deg);
    k_dinv   <<<(GN + 255) / 256,        256, 0, stream>>>(deg, dinv);
    k_s      <<<BN, 256, 0, stream>>>(row, col, dinv, h, s);
    k_out    <<<BN * NOUTN, 64, 0, stream>>>(s, W_gcn, b_gcn, W_out, b_out, out);
}